// Round 1
// 735.222 us; speedup vs baseline: 1.2346x; 1.2346x over previous
//
#include <hip/hip_runtime.h>

#define NN 100000
#define NE 1600000
#define NT (2 * NN)        // combined nodes (sr | tg+NN)
#define ET (2 * NE)        // combined edges
#define DIM 128
#define NS 15000
#define SB2 ((NT + 255) / 256)  // 782 scan blocks
#define PAD 136                 // LDS row stride in bf16
#define NRANGE 8                // dst-range partition (1 range <-> 1 XCD)
#define RSZ (NT / NRANGE)       // 25000 nodes/range; csr slice = ET/8*4B = 1.6MB < 4MB L2
#define NCHUNK (ET / 1024)      // 3125 edge chunks of 1024

typedef __attribute__((ext_vector_type(8))) short frag_ab;  // 8 bf16
typedef __attribute__((ext_vector_type(4))) float frag_cd;  // 4 f32
typedef __attribute__((ext_vector_type(4))) int i4;

__device__ __forceinline__ unsigned short f2bf(float f) {  // RNE
    unsigned int u = __float_as_uint(f);
    u += 0x7fff + ((u >> 16) & 1);
    return (unsigned short)(u >> 16);
}
__device__ __forceinline__ float bflo(unsigned int u) { return __uint_as_float(u << 16); }
__device__ __forceinline__ float bfhi(unsigned int u) { return __uint_as_float(u & 0xffff0000u); }

// ---------------- degree + per-edge rank (both graphs in one pass) ----------------
// rank[e] = #earlier edges with same dst  -> fill needs no atomics at all.
__global__ __launch_bounds__(256) void count_k(const int* __restrict__ e_sr,
                                               const int* __restrict__ e_tg,
                                               int* cnt, int* __restrict__ rank) {
    int e = blockIdx.x * 256 + threadIdx.x;
    if (e >= ET) return;
    int t;
    if (e < NE) t = e_sr[NE + e];            // dst_sr
    else        t = e_tg[e] + NN;            // dst_tg
    rank[e] = atomicAdd(&cnt[t], 1);
}

__global__ __launch_bounds__(256) void dinv_k(const int* __restrict__ cnt, float* dinv) {
    int i = blockIdx.x * 256 + threadIdx.x;
    if (i < NT) dinv[i] = rsqrtf((float)(cnt[i] + 1));  // +1 self-loop
}

// ---------------- scan: row_ptr = exclusive_scan(cnt) ----------------
__global__ __launch_bounds__(256) void scanA_k(const int* __restrict__ cnt, int* bsum) {
    __shared__ int s[256];
    const int t = threadIdx.x;
    const int i = blockIdx.x * 256 + t;
    s[t] = (i < NT) ? cnt[i] : 0;
    __syncthreads();
    for (int off = 128; off > 0; off >>= 1) {
        if (t < off) s[t] += s[t + off];
        __syncthreads();
    }
    if (t == 0) bsum[blockIdx.x] = s[0];
}

__global__ __launch_bounds__(1024) void scanB_k(int* bsum, int* row_ptr) {
    __shared__ int s[1024];
    const int t = threadIdx.x;
    const int v = (t < SB2) ? bsum[t] : 0;
    s[t] = v;
    __syncthreads();
    for (int off = 1; off < 1024; off <<= 1) {
        int add = (t >= off) ? s[t - off] : 0;
        __syncthreads();
        s[t] += add;
        __syncthreads();
    }
    if (t < SB2) bsum[t] = s[t] - v;        // exclusive
    if (t == SB2 - 1) row_ptr[NT] = s[t];   // == ET
}

__global__ __launch_bounds__(256) void scanC_k(const int* __restrict__ cnt,
                                               const int* __restrict__ bsum,
                                               int* row_ptr) {
    __shared__ int s[256];
    const int t = threadIdx.x;
    const int i = blockIdx.x * 256 + t;
    const int v = (i < NT) ? cnt[i] : 0;
    s[t] = v;
    __syncthreads();
    for (int off = 1; off < 256; off <<= 1) {
        int add = (t >= off) ? s[t - off] : 0;
        __syncthreads();
        s[t] += add;
        __syncthreads();
    }
    if (i < NT) row_ptr[i] = bsum[blockIdx.x] + s[t] - v;
}

// ---------------- fill: dst-range partitioned, atomic-free ----------------
// range r (<-> XCD r via blockIdx&7 round-robin) handles dst in [r*RSZ,(r+1)*RSZ):
// its csr_src slice (1.6MB) stays resident in one L2, so the 16 scattered 4B
// stores per 64B line coalesce into ONE writeback (was: 1 writeback per store,
// 211MB HBM write). Edge list re-read x8 is L3-resident (25.6MB << 256MB); read
// non-temporally to avoid evicting dirty csr lines from L2.
__global__ __launch_bounds__(256) void fill_r_k(const int* __restrict__ e_sr,
                                                const int* __restrict__ e_tg,
                                                const int* __restrict__ rank,
                                                const int* __restrict__ row_ptr,
                                                int* __restrict__ csr_src) {
    const int r = blockIdx.x & (NRANGE - 1);
    const int chunk = blockIdx.x >> 3;
    const int lo = r * RSZ;
    const int hi = lo + RSZ;
    const int e0 = chunk * 1024 + (threadIdx.x << 2);  // 4 edges/thread, 16B aligned
    i4 s4, d4;
    if (e0 < NE) {
        s4 = __builtin_nontemporal_load((const i4*)&e_sr[e0]);
        d4 = __builtin_nontemporal_load((const i4*)&e_sr[NE + e0]);
    } else {
        s4 = __builtin_nontemporal_load((const i4*)&e_tg[e0 - NE]);
        d4 = __builtin_nontemporal_load((const i4*)&e_tg[e0]);
        s4 += NN;
        d4 += NN;
    }
    const i4 rk = __builtin_nontemporal_load((const i4*)&rank[e0]);
#pragma unroll
    for (int j = 0; j < 4; ++j) {
        const int t = d4[j];
        if (t >= lo && t < hi)
            csr_src[row_ptr[t] + rk[j]] = s4[j];
    }
}

// ---------------- fp32 -> bf16 conversion (both embeddings) ----------------
__global__ __launch_bounds__(256) void convX_k(const float* __restrict__ emb_sr,
                                               const float* __restrict__ emb_tg,
                                               unsigned short* __restrict__ xb) {
    const int i = blockIdx.x * 256 + threadIdx.x;  // over NT*32 float4s
    if (i >= NT * 32) return;
    const int node = i >> 5;
    float4 v = (node < NN) ? ((const float4*)emb_sr)[i]
                           : ((const float4*)emb_tg)[i - NN * 32];
    ushort4 o;
    o.x = f2bf(v.x); o.y = f2bf(v.y); o.z = f2bf(v.z); o.w = f2bf(v.w);
    ((ushort4*)xb)[i] = o;
}

// Wt[n][k] = bf16(W[k][n])
__global__ __launch_bounds__(256) void convW_k(const float* __restrict__ W,
                                               unsigned short* __restrict__ wt) {
    int i = blockIdx.x * 256 + threadIdx.x;
    if (i >= DIM * DIM) return;
    const int n = i & 127, k = i >> 7;
    wt[n * DIM + k] = f2bf(W[k * DIM + n]);
}

// ---------------- MFMA GEMM + dinv scaling: Gb = dinv ⊙ (Xb @ W) ----------------
__global__ __launch_bounds__(256) void gemm_mfma_k(const unsigned short* __restrict__ Xb,
                                                   const unsigned short* __restrict__ Wt,
                                                   const float* __restrict__ dinv,
                                                   unsigned short* __restrict__ Gb) {
    __shared__ unsigned short xs[64 * PAD];   // 17.4 KB
    __shared__ unsigned short ws[128 * PAD];  // 34.8 KB
    const int tid = threadIdx.x;
    const int row0 = blockIdx.x * 64;

    for (int i = tid; i < 128 * 16; i += 256) {
        const int r = i >> 4, o = i & 15;
        *(uint4*)&ws[r * PAD + o * 8] = *(const uint4*)&Wt[r * DIM + o * 8];
    }
    for (int i = tid; i < 64 * 16; i += 256) {
        const int r = i >> 4, o = i & 15;
        int gr = row0 + r; if (gr >= NT) gr = NT - 1;
        *(uint4*)&xs[r * PAD + o * 8] = *(const uint4*)&Xb[gr * DIM + o * 8];
    }
    __syncthreads();

    const int wave = tid >> 6;
    const int lane = tid & 63;
    const int m = lane & 15;
    const int quad = lane >> 4;
    const int rbase = wave * 16;

    frag_cd acc[8];
#pragma unroll
    for (int ct = 0; ct < 8; ct++) acc[ct] = (frag_cd){0.f, 0.f, 0.f, 0.f};

#pragma unroll
    for (int ks = 0; ks < 4; ks++) {
        const frag_ab a = *(const frag_ab*)&xs[(rbase + m) * PAD + ks * 32 + quad * 8];
#pragma unroll
        for (int ct = 0; ct < 8; ct++) {
            const frag_ab b = *(const frag_ab*)&ws[(ct * 16 + m) * PAD + ks * 32 + quad * 8];
            acc[ct] = __builtin_amdgcn_mfma_f32_16x16x32_bf16(a, b, acc[ct], 0, 0, 0);
        }
    }

    // C/D layout: col = lane&15, row = quad*4 + reg
#pragma unroll
    for (int r = 0; r < 4; r++) {
        const int grow = row0 + rbase + quad * 4 + r;
        if (grow < NT) {
            const float dv = dinv[grow];
#pragma unroll
            for (int ct = 0; ct < 8; ct++)
                Gb[grow * DIM + ct * 16 + m] = f2bf(dv * acc[ct][r]);
        }
    }
}

// ---------------- fused pull (weightless gather) + residual + ReLU ----------------
// out[t] = relu( dinv[t]*(g[t] + Σ g[src]) + g[t]*sqrt(deg[t]) )
template <bool OUT_BF16>
__global__ __launch_bounds__(256) void pull_k(const int* __restrict__ row_ptr,
                                              const int* __restrict__ csr_src,
                                              const float* __restrict__ dinv,
                                              const unsigned short* __restrict__ Gb,
                                              float* __restrict__ outf,
                                              unsigned short* __restrict__ outb) {
    const int node = (blockIdx.x * 256 + threadIdx.x) >> 6;
    if (node >= NT) return;
    const int lane = threadIdx.x & 63;
    const unsigned int* __restrict__ G2 = (const unsigned int*)Gb;

    const int beg = row_ptr[node];
    const int end = row_ptr[node + 1];
    const float d = dinv[node];
    const float sq = 1.0f / d;  // sqrt(deg)

    const unsigned int gu = G2[node * 64 + lane];
    float sx = bflo(gu);  // self-loop term g[t]
    float sy = bfhi(gu);
    const float hx = sx * sq;  // residual h[t] = g[t]*sqrt(deg)
    const float hy = sy * sq;

    for (int base = beg; base < end; base += 64) {
        int rem = end - base; if (rem > 64) rem = 64;
        const int sl = (lane < rem) ? csr_src[base + lane] : 0;
        int j = 0;
        for (; j + 4 <= rem; j += 4) {
            const int s0 = __shfl(sl, j + 0);
            const int s1 = __shfl(sl, j + 1);
            const int s2 = __shfl(sl, j + 2);
            const int s3 = __shfl(sl, j + 3);
            const unsigned int m0 = G2[s0 * 64 + lane];
            const unsigned int m1 = G2[s1 * 64 + lane];
            const unsigned int m2 = G2[s2 * 64 + lane];
            const unsigned int m3 = G2[s3 * 64 + lane];
            sx += bflo(m0) + bflo(m1) + bflo(m2) + bflo(m3);
            sy += bfhi(m0) + bfhi(m1) + bfhi(m2) + bfhi(m3);
        }
        for (; j < rem; ++j) {
            const int s = __shfl(sl, j);
            const unsigned int mu = G2[s * 64 + lane];
            sx += bflo(mu);
            sy += bfhi(mu);
        }
    }
    const float ax = fmaxf(d * sx + hx, 0.f);
    const float ay = fmaxf(d * sy + hy, 0.f);
    if (OUT_BF16) {
        ((unsigned int*)outb)[node * 64 + lane] =
            (unsigned int)f2bf(ax) | ((unsigned int)f2bf(ay) << 16);
    } else {
        float2 o; o.x = ax; o.y = ay;
        ((float2*)outf)[node * 64 + lane] = o;
    }
}

// ---------------- seed gather ----------------
__global__ __launch_bounds__(256) void gather_k(const int* __restrict__ seeds,
                                                const float* __restrict__ ent,
                                                float* __restrict__ out, int node_off) {
    const int gid = blockIdx.x * 256 + threadIdx.x;
    const int s = gid >> 5;
    if (s >= NS) return;
    const int q = gid & 31;
    ((float4*)out)[s * 32 + q] =
        ((const float4*)ent)[(seeds[s] + node_off) * 32 + q];
}

extern "C" void kernel_launch(void* const* d_in, const int* in_sizes, int n_in,
                              void* d_out, int out_size, void* d_ws, size_t ws_size,
                              hipStream_t stream) {
    const int* sr_seeds = (const int*)d_in[0];
    const int* tg_seeds = (const int*)d_in[1];
    const int* edges_sr = (const int*)d_in[2];
    const int* edges_tg = (const int*)d_in[3];
    const float* emb_sr = (const float*)d_in[4];
    const float* emb_tg = (const float*)d_in[5];
    const float* W0 = (const float*)d_in[6];
    const float* W1 = (const float*)d_in[7];
    float* out = (float*)d_out;

    // ws layout (4B words): cnt[200704] dinv[200704] row_ptr[200704]
    // bsum[1024] csr_src[ET] wt0+wt1[16384 words] hb[NT*DIM ushort]
    // total = 16,619,520 words = 66.5 MB (R3-proven footprint)
    // rank[ET] aliases hb: written by count_k, consumed by fill_r_k,
    // both strictly before gemm layer-1 writes hb. Same footprint.
    int* cnt = (int*)d_ws;
    float* dinv = (float*)(cnt + 200704);
    int* row_ptr = (int*)(dinv + 200704);
    int* bsum = row_ptr + 200704;
    int* csr_src = bsum + 1024;
    unsigned short* wt0 = (unsigned short*)(csr_src + ET);
    unsigned short* wt1 = wt0 + DIM * DIM;
    unsigned short* hb = wt1 + DIM * DIM;  // [NT*DIM] bf16
    int* rank = (int*)hb;                  // [ET] ints, dead before gemm layer 1

    // output layout (floats): sr_seed | tg_seed | ent [NT, DIM]
    float* sr_seed_out = out;
    float* tg_seed_out = out + (long long)NS * DIM;
    float* ent = out + (long long)2 * NS * DIM;
    // x1 (bf16) borrows the ent region: consumed by layer-2 gemm before
    // pull<false> overwrites the region with the final f32 ent.
    unsigned short* xb = (unsigned short*)ent;

    const int gE = (ET + 255) / 256;       // 12500
    const int gGemm = (NT + 63) / 64;      // 3125
    const int gPull = NT / 4;              // 50000
    const int gElem = (NT * 32 + 255) / 256;

    convW_k<<<(DIM * DIM + 255) / 256, 256, 0, stream>>>(W0, wt0);
    convW_k<<<(DIM * DIM + 255) / 256, 256, 0, stream>>>(W1, wt1);

    hipMemsetAsync(cnt, 0, NT * sizeof(int), stream);
    count_k<<<gE, 256, 0, stream>>>(edges_sr, edges_tg, cnt, rank);
    dinv_k<<<SB2, 256, 0, stream>>>(cnt, dinv);
    scanA_k<<<SB2, 256, 0, stream>>>(cnt, bsum);
    scanB_k<<<1, 1024, 0, stream>>>(bsum, row_ptr);
    scanC_k<<<SB2, 256, 0, stream>>>(cnt, bsum, row_ptr);
    fill_r_k<<<NRANGE * NCHUNK, 256, 0, stream>>>(edges_sr, edges_tg, rank,
                                                  row_ptr, csr_src);

    convX_k<<<gElem, 256, 0, stream>>>(emb_sr, emb_tg, xb);  // x0 -> xb (ent region)

    // layer 1: g = dinv ⊙ (x0@W0) -> hb ; x1(bf16) -> xb
    gemm_mfma_k<<<gGemm, 256, 0, stream>>>(xb, wt0, dinv, hb);
    pull_k<true><<<gPull, 256, 0, stream>>>(row_ptr, csr_src, dinv, hb, nullptr, xb);
    // layer 2: g = dinv ⊙ (x1@W1) -> hb ; ent(f32) overwrites xb's region
    gemm_mfma_k<<<gGemm, 256, 0, stream>>>(xb, wt1, dinv, hb);
    pull_k<false><<<gPull, 256, 0, stream>>>(row_ptr, csr_src, dinv, hb, ent, nullptr);

    const int gSeed = (NS * 32 + 255) / 256;
    gather_k<<<gSeed, 256, 0, stream>>>(sr_seeds, ent, sr_seed_out, 0);
    gather_k<<<gSeed, 256, 0, stream>>>(tg_seeds, ent, tg_seed_out, NN);
}

// Round 3
// 642.255 us; speedup vs baseline: 1.4133x; 1.1448x over previous
//
#include <hip/hip_runtime.h>

#define NN 100000
#define NE 1600000
#define NT (2 * NN)        // combined nodes (sr | tg+NN)
#define ET (2 * NE)        // combined edges
#define DIM 128
#define NS 15000
#define SB2 ((NT + 255) / 256)  // 782 scan blocks
#define PAD 136                 // LDS row stride in bf16
#define NRANGE 8                // dst-range partition (1 range <-> 1 XCD)
#define RSZ (NT / NRANGE)       // 25000 nodes/range; LDS hist = 100 KB (<160 KB/CU)
#define CH 32                   // edge chunks
#define CI4 (ET / 4 / CH)       // 25000 i4-groups per chunk (exact)
#define NE4 (NE / 4)            // 400000

typedef __attribute__((ext_vector_type(8))) short frag_ab;  // 8 bf16
typedef __attribute__((ext_vector_type(4))) float frag_cd;  // 4 f32
typedef __attribute__((ext_vector_type(4))) int i4;

__device__ __forceinline__ unsigned short f2bf(float f) {  // RNE
    unsigned int u = __float_as_uint(f);
    u += 0x7fff + ((u >> 16) & 1);
    return (unsigned short)(u >> 16);
}
__device__ __forceinline__ float bflo(unsigned int u) { return __uint_as_float(u << 16); }
__device__ __forceinline__ float bfhi(unsigned int u) { return __uint_as_float(u & 0xffff0000u); }

// ---------------- pass 1: per-(range,chunk) LDS histogram -> P[c][node] ----------------
// Zero global atomics. Block (r,c): count chunk c's dsts falling in range r.
// P layout [CH][NT] so each block writes one contiguous 100 KB slice.
__global__ __launch_bounds__(1024) void hist_k(const int* __restrict__ e_sr,
                                               const int* __restrict__ e_tg,
                                               int* __restrict__ P) {
    __shared__ int lc[RSZ];
    const int r = blockIdx.x & (NRANGE - 1);   // low bits -> XCD round-robin
    const int c = blockIdx.x >> 3;
    const int lo = r * RSZ;
    for (int i = threadIdx.x; i < RSZ; i += 1024) lc[i] = 0;
    __syncthreads();
    const int base = c * CI4;  // i4 units into the combined edge list
    // dst i4 index: sr chunks (c<16): e_sr + NE4 + base + v ; tg: e_tg + base + v
    for (int v = threadIdx.x; v < CI4; v += 1024) {
        i4 d4;
        if (c < 16) {
            d4 = __builtin_nontemporal_load((const i4*)e_sr + NE4 + base + v);
        } else {
            d4 = __builtin_nontemporal_load((const i4*)e_tg + base + v);
            d4 += NN;
        }
#pragma unroll
        for (int j = 0; j < 4; ++j) {
            const int t = d4[j] - lo;
            if ((unsigned)t < RSZ) atomicAdd(&lc[t], 1);
        }
    }
    __syncthreads();
    for (int i = threadIdx.x; i < RSZ; i += 1024) P[c * NT + lo + i] = lc[i];
}

// ---------------- cnt = sum_c P[c][n] ; fused dinv ----------------
__global__ __launch_bounds__(256) void reduce_k(const int* __restrict__ P,
                                                int* __restrict__ cnt,
                                                float* __restrict__ dinv) {
    const int i = blockIdx.x * 256 + threadIdx.x;
    if (i >= NT) return;
    int s = 0;
#pragma unroll
    for (int c = 0; c < CH; ++c) s += P[c * NT + i];
    cnt[i] = s;
    dinv[i] = rsqrtf((float)(s + 1));  // +1 self-loop
}

// ---------------- scan: row_ptr = exclusive_scan(cnt) ----------------
__global__ __launch_bounds__(256) void scanA_k(const int* __restrict__ cnt, int* bsum) {
    __shared__ int s[256];
    const int t = threadIdx.x;
    const int i = blockIdx.x * 256 + t;
    s[t] = (i < NT) ? cnt[i] : 0;
    __syncthreads();
    for (int off = 128; off > 0; off >>= 1) {
        if (t < off) s[t] += s[t + off];
        __syncthreads();
    }
    if (t == 0) bsum[blockIdx.x] = s[0];
}

__global__ __launch_bounds__(1024) void scanB_k(int* bsum, int* row_ptr) {
    __shared__ int s[1024];
    const int t = threadIdx.x;
    const int v = (t < SB2) ? bsum[t] : 0;
    s[t] = v;
    __syncthreads();
    for (int off = 1; off < 1024; off <<= 1) {
        int add = (t >= off) ? s[t - off] : 0;
        __syncthreads();
        s[t] += add;
        __syncthreads();
    }
    if (t < SB2) bsum[t] = s[t] - v;        // exclusive
    if (t == SB2 - 1) row_ptr[NT] = s[t];   // == ET
}

__global__ __launch_bounds__(256) void scanC_k(const int* __restrict__ cnt,
                                               const int* __restrict__ bsum,
                                               int* row_ptr) {
    __shared__ int s[256];
    const int t = threadIdx.x;
    const int i = blockIdx.x * 256 + t;
    const int v = (i < NT) ? cnt[i] : 0;
    s[t] = v;
    __syncthreads();
    for (int off = 1; off < 256; off <<= 1) {
        int add = (t >= off) ? s[t - off] : 0;
        __syncthreads();
        s[t] += add;
        __syncthreads();
    }
    if (i < NT) row_ptr[i] = bsum[blockIdx.x] + s[t] - v;
}

// ---------------- base[c][n] = row_ptr[n] + excl_scan_c(P) (in place) ----------------
__global__ __launch_bounds__(256) void base_k(int* __restrict__ P,
                                              const int* __restrict__ row_ptr) {
    const int i = blockIdx.x * 256 + threadIdx.x;
    if (i >= NT) return;
    int run = row_ptr[i];
#pragma unroll
    for (int c = 0; c < CH; ++c) {
        const int v = P[c * NT + i];
        P[c * NT + i] = run;
        run += v;
    }
}

// ---------------- pass 2: fill via LDS cursors, atomic-free globally ----------------
// Block (r,c): cursors = base[c][range] in LDS; slots within each (node,chunk)
// sub-range assigned by LDS atomic order (any bijection is valid — segment_sum
// is order-independent). csr writes stay in one XCD's L2 (range partition),
// preserving the round-1 write-coalescing win.
__global__ __launch_bounds__(1024) void fillp_k(const int* __restrict__ e_sr,
                                                const int* __restrict__ e_tg,
                                                const int* __restrict__ P,  // = base
                                                int* __restrict__ csr_src) {
    __shared__ int cur[RSZ];
    const int r = blockIdx.x & (NRANGE - 1);
    const int c = blockIdx.x >> 3;
    const int lo = r * RSZ;
    for (int i = threadIdx.x; i < RSZ; i += 1024) cur[i] = P[c * NT + lo + i];
    __syncthreads();
    const int base = c * CI4;
    for (int v = threadIdx.x; v < CI4; v += 1024) {
        i4 s4, d4;
        if (c < 16) {
            s4 = __builtin_nontemporal_load((const i4*)e_sr + base + v);
            d4 = __builtin_nontemporal_load((const i4*)e_sr + NE4 + base + v);
        } else {
            s4 = __builtin_nontemporal_load((const i4*)e_tg + base + v - NE4);
            d4 = __builtin_nontemporal_load((const i4*)e_tg + base + v);
            s4 += NN;
            d4 += NN;
        }
#pragma unroll
        for (int j = 0; j < 4; ++j) {
            const int t = d4[j] - lo;
            if ((unsigned)t < RSZ) {
                const int pos = atomicAdd(&cur[t], 1);
                csr_src[pos] = s4[j];  // plain store: wants L2 residency
            }
        }
    }
}

// ---------------- fp32 -> bf16 conversion (both embeddings) ----------------
__global__ __launch_bounds__(256) void convX_k(const float* __restrict__ emb_sr,
                                               const float* __restrict__ emb_tg,
                                               unsigned short* __restrict__ xb) {
    const int i = blockIdx.x * 256 + threadIdx.x;  // over NT*32 float4s
    if (i >= NT * 32) return;
    const int node = i >> 5;
    float4 v = (node < NN) ? ((const float4*)emb_sr)[i]
                           : ((const float4*)emb_tg)[i - NN * 32];
    ushort4 o;
    o.x = f2bf(v.x); o.y = f2bf(v.y); o.z = f2bf(v.z); o.w = f2bf(v.w);
    ((ushort4*)xb)[i] = o;
}

// Wt[n][k] = bf16(W[k][n])
__global__ __launch_bounds__(256) void convW_k(const float* __restrict__ W,
                                               unsigned short* __restrict__ wt) {
    int i = blockIdx.x * 256 + threadIdx.x;
    if (i >= DIM * DIM) return;
    const int n = i & 127, k = i >> 7;
    wt[n * DIM + k] = f2bf(W[k * DIM + n]);
}

// ---------------- MFMA GEMM + dinv scaling: Gb = dinv ⊙ (Xb @ W) ----------------
__global__ __launch_bounds__(256) void gemm_mfma_k(const unsigned short* __restrict__ Xb,
                                                   const unsigned short* __restrict__ Wt,
                                                   const float* __restrict__ dinv,
                                                   unsigned short* __restrict__ Gb) {
    __shared__ unsigned short xs[64 * PAD];   // 17.4 KB
    __shared__ unsigned short ws[128 * PAD];  // 34.8 KB
    const int tid = threadIdx.x;
    const int row0 = blockIdx.x * 64;

    for (int i = tid; i < 128 * 16; i += 256) {
        const int r = i >> 4, o = i & 15;
        *(uint4*)&ws[r * PAD + o * 8] = *(const uint4*)&Wt[r * DIM + o * 8];
    }
    for (int i = tid; i < 64 * 16; i += 256) {
        const int r = i >> 4, o = i & 15;
        int gr = row0 + r; if (gr >= NT) gr = NT - 1;
        *(uint4*)&xs[r * PAD + o * 8] = *(const uint4*)&Xb[gr * DIM + o * 8];
    }
    __syncthreads();

    const int wave = tid >> 6;
    const int lane = tid & 63;
    const int m = lane & 15;
    const int quad = lane >> 4;
    const int rbase = wave * 16;

    frag_cd acc[8];
#pragma unroll
    for (int ct = 0; ct < 8; ct++) acc[ct] = (frag_cd){0.f, 0.f, 0.f, 0.f};

#pragma unroll
    for (int ks = 0; ks < 4; ks++) {
        const frag_ab a = *(const frag_ab*)&xs[(rbase + m) * PAD + ks * 32 + quad * 8];
#pragma unroll
        for (int ct = 0; ct < 8; ct++) {
            const frag_ab b = *(const frag_ab*)&ws[(ct * 16 + m) * PAD + ks * 32 + quad * 8];
            acc[ct] = __builtin_amdgcn_mfma_f32_16x16x32_bf16(a, b, acc[ct], 0, 0, 0);
        }
    }

    // C/D layout: col = lane&15, row = quad*4 + reg
#pragma unroll
    for (int r = 0; r < 4; r++) {
        const int grow = row0 + rbase + quad * 4 + r;
        if (grow < NT) {
            const float dv = dinv[grow];
#pragma unroll
            for (int ct = 0; ct < 8; ct++)
                Gb[grow * DIM + ct * 16 + m] = f2bf(dv * acc[ct][r]);
        }
    }
}

// ---------------- fused pull (weightless gather) + residual + ReLU ----------------
// out[t] = relu( dinv[t]*(g[t] + Σ g[src]) + g[t]*sqrt(deg[t]) )
template <bool OUT_BF16>
__global__ __launch_bounds__(256) void pull_k(const int* __restrict__ row_ptr,
                                              const int* __restrict__ csr_src,
                                              const float* __restrict__ dinv,
                                              const unsigned short* __restrict__ Gb,
                                              float* __restrict__ outf,
                                              unsigned short* __restrict__ outb) {
    const int node = (blockIdx.x * 256 + threadIdx.x) >> 6;
    if (node >= NT) return;
    const int lane = threadIdx.x & 63;
    const unsigned int* __restrict__ G2 = (const unsigned int*)Gb;

    const int beg = row_ptr[node];
    const int end = row_ptr[node + 1];
    const float d = dinv[node];
    const float sq = 1.0f / d;  // sqrt(deg)

    const unsigned int gu = G2[node * 64 + lane];
    float sx = bflo(gu);  // self-loop term g[t]
    float sy = bfhi(gu);
    const float hx = sx * sq;  // residual h[t] = g[t]*sqrt(deg)
    const float hy = sy * sq;

    for (int base = beg; base < end; base += 64) {
        int rem = end - base; if (rem > 64) rem = 64;
        const int sl = (lane < rem) ? csr_src[base + lane] : 0;
        int j = 0;
        for (; j + 4 <= rem; j += 4) {
            const int s0 = __shfl(sl, j + 0);
            const int s1 = __shfl(sl, j + 1);
            const int s2 = __shfl(sl, j + 2);
            const int s3 = __shfl(sl, j + 3);
            const unsigned int m0 = G2[s0 * 64 + lane];
            const unsigned int m1 = G2[s1 * 64 + lane];
            const unsigned int m2 = G2[s2 * 64 + lane];
            const unsigned int m3 = G2[s3 * 64 + lane];
            sx += bflo(m0) + bflo(m1) + bflo(m2) + bflo(m3);
            sy += bfhi(m0) + bfhi(m1) + bfhi(m2) + bfhi(m3);
        }
        for (; j < rem; ++j) {
            const int s = __shfl(sl, j);
            const unsigned int mu = G2[s * 64 + lane];
            sx += bflo(mu);
            sy += bfhi(mu);
        }
    }
    const float ax = fmaxf(d * sx + hx, 0.f);
    const float ay = fmaxf(d * sy + hy, 0.f);
    if (OUT_BF16) {
        ((unsigned int*)outb)[node * 64 + lane] =
            (unsigned int)f2bf(ax) | ((unsigned int)f2bf(ay) << 16);
    } else {
        float2 o; o.x = ax; o.y = ay;
        ((float2*)outf)[node * 64 + lane] = o;
    }
}

// ---------------- seed gather ----------------
__global__ __launch_bounds__(256) void gather_k(const int* __restrict__ seeds,
                                                const float* __restrict__ ent,
                                                float* __restrict__ out, int node_off) {
    const int gid = blockIdx.x * 256 + threadIdx.x;
    const int s = gid >> 5;
    if (s >= NS) return;
    const int q = gid & 31;
    ((float4*)out)[s * 32 + q] =
        ((const float4*)ent)[(seeds[s] + node_off) * 32 + q];
}

extern "C" void kernel_launch(void* const* d_in, const int* in_sizes, int n_in,
                              void* d_out, int out_size, void* d_ws, size_t ws_size,
                              hipStream_t stream) {
    const int* sr_seeds = (const int*)d_in[0];
    const int* tg_seeds = (const int*)d_in[1];
    const int* edges_sr = (const int*)d_in[2];
    const int* edges_tg = (const int*)d_in[3];
    const float* emb_sr = (const float*)d_in[4];
    const float* emb_tg = (const float*)d_in[5];
    const float* W0 = (const float*)d_in[6];
    const float* W1 = (const float*)d_in[7];
    float* out = (float*)d_out;

    // ws layout (4B words): cnt[200704] dinv[200704] row_ptr[200704]
    // bsum[1024] csr_src[ET] wt0+wt1[16384 words] hb[NT*DIM ushort]
    // total = 16,619,520 words = 66.5 MB (R3-proven footprint, unchanged)
    // P[CH][NT] (6.4M words = 25.6 MB) aliases hb: written by hist_k,
    // scanned in-place by base_k, consumed by fillp_k — all strictly
    // before gemm layer-1 writes hb.
    int* cnt = (int*)d_ws;
    float* dinv = (float*)(cnt + 200704);
    int* row_ptr = (int*)(dinv + 200704);
    int* bsum = row_ptr + 200704;
    int* csr_src = bsum + 1024;
    unsigned short* wt0 = (unsigned short*)(csr_src + ET);
    unsigned short* wt1 = wt0 + DIM * DIM;
    unsigned short* hb = wt1 + DIM * DIM;  // [NT*DIM] bf16
    int* P = (int*)hb;                     // [CH][NT] ints, dead before gemm 1

    // output layout (floats): sr_seed | tg_seed | ent [NT, DIM]
    float* sr_seed_out = out;
    float* tg_seed_out = out + (long long)NS * DIM;
    float* ent = out + (long long)2 * NS * DIM;
    // x1 (bf16) borrows the ent region: consumed by layer-2 gemm before
    // pull<false> overwrites the region with the final f32 ent.
    unsigned short* xb = (unsigned short*)ent;

    const int gGemm = (NT + 63) / 64;      // 3125
    const int gPull = NT / 4;              // 50000
    const int gElem = (NT * 32 + 255) / 256;

    convW_k<<<(DIM * DIM + 255) / 256, 256, 0, stream>>>(W0, wt0);
    convW_k<<<(DIM * DIM + 255) / 256, 256, 0, stream>>>(W1, wt1);

    hist_k<<<NRANGE * CH, 1024, 0, stream>>>(edges_sr, edges_tg, P);
    reduce_k<<<SB2, 256, 0, stream>>>(P, cnt, dinv);
    scanA_k<<<SB2, 256, 0, stream>>>(cnt, bsum);
    scanB_k<<<1, 1024, 0, stream>>>(bsum, row_ptr);
    scanC_k<<<SB2, 256, 0, stream>>>(cnt, bsum, row_ptr);
    base_k<<<SB2, 256, 0, stream>>>(P, row_ptr);
    fillp_k<<<NRANGE * CH, 1024, 0, stream>>>(edges_sr, edges_tg, P, csr_src);

    convX_k<<<gElem, 256, 0, stream>>>(emb_sr, emb_tg, xb);  // x0 -> xb (ent region)

    // layer 1: g = dinv ⊙ (x0@W0) -> hb ; x1(bf16) -> xb
    gemm_mfma_k<<<gGemm, 256, 0, stream>>>(xb, wt0, dinv, hb);
    pull_k<true><<<gPull, 256, 0, stream>>>(row_ptr, csr_src, dinv, hb, nullptr, xb);
    // layer 2: g = dinv ⊙ (x1@W1) -> hb ; ent(f32) overwrites xb's region
    gemm_mfma_k<<<gGemm, 256, 0, stream>>>(xb, wt1, dinv, hb);
    pull_k<false><<<gPull, 256, 0, stream>>>(row_ptr, csr_src, dinv, hb, ent, nullptr);

    const int gSeed = (NS * 32 + 255) / 256;
    gather_k<<<gSeed, 256, 0, stream>>>(sr_seeds, ent, sr_seed_out, 0);
    gather_k<<<gSeed, 256, 0, stream>>>(tg_seeds, ent, tg_seed_out, NN);
}